// Round 2
// 663.895 us; speedup vs baseline: 1.3285x; 1.3285x over previous
//
#include <hip/hip_runtime.h>
#include <math.h>

#define BETA 10.0f
#define ALPHA 0.01f

typedef float f4 __attribute__((ext_vector_type(4)));

// --- monotone float <-> uint code for exact order statistics ---
__device__ __forceinline__ unsigned enc_f(float f) {
    unsigned b = __float_as_uint(f);
    return b ^ ((b >> 31) ? 0xFFFFFFFFu : 0x80000000u);
}
__device__ __forceinline__ float dec_f(unsigned u) {
    unsigned b = (u & 0x80000000u) ? (u ^ 0x80000000u) : ~u;
    return __uint_as_float(b);
}
__device__ __forceinline__ float sigmoidf(float z) {
    return 1.0f / (1.0f + expf(-z));
}

// h[row] = dot(W[row, :], x) — one wave (64 lanes) per row, float4 nt loads.
template <int NC4>
__global__ __launch_bounds__(256) void matvec_kernel(
    const float* __restrict__ W, const float* __restrict__ x,
    float* __restrict__ h, int nrows) {
    int gid  = blockIdx.x * blockDim.x + threadIdx.x;
    int wave = gid >> 6;
    int lane = threadIdx.x & 63;
    if (wave >= nrows) return;
    const f4* Wr = (const f4*)(W + (size_t)wave * (size_t)(NC4 * 4));
    const f4* x4 = (const f4*)x;
    float acc = 0.f;
#pragma unroll 4
    for (int k = 0; k < NC4 / 64; ++k) {
        int i = lane + (k << 6);
        f4 w  = __builtin_nontemporal_load(&Wr[i]);  // W is read-once: stream it
        f4 xv = x4[i];                               // x is tiny & reused: cache it
        acc = fmaf(w.x, xv.x, acc);
        acc = fmaf(w.y, xv.y, acc);
        acc = fmaf(w.z, xv.z, acc);
        acc = fmaf(w.w, xv.w, acc);
    }
#pragma unroll
    for (int off = 32; off > 0; off >>= 1) acc += __shfl_down(acc, off);
    if (lane == 0) h[wave] = acc;
}

// Exact top-K sparsemoid via 4-round radix-256 select.
// 1024 threads, M = n/1024 codes per thread held in REGISTERS (compile-time M,
// fully unrolled — avoids the scratch spill of runtime-indexed arrays).
// Round b (MSB->LSB byte): histogram candidate codes' byte b into LDS,
// suffix-scan 256 bins (wave shfl scan + 4 wave totals), pick the bin holding
// the K_rem-th largest, narrow prefix. After 4 rounds prefix == code of the
// K-th largest element exactly.
template <int M>
__device__ __forceinline__ void topk_body(
    const float* __restrict__ h, float* __restrict__ y, int K, int masked) {
    __shared__ int s_hist[256];
    __shared__ int s_scum[257];
    __shared__ int s_wtot[4];
    __shared__ int s_sel, s_above;

    int tid  = threadIdx.x;   // 0..1023
    int lane = tid & 63;
    int w    = tid >> 6;

    unsigned codes[M];
#pragma unroll
    for (int i = 0; i < M; ++i) codes[i] = enc_f(h[tid + (i << 10)]);

    unsigned prefix = 0;
    int K_rem = K;

#pragma unroll
    for (int b = 3; b >= 0; --b) {
        const int shift = b << 3;
        const unsigned hi_mask = (b == 3) ? 0u : (0xFFFFFFFFu << (shift + 8));

        if (tid < 256) s_hist[tid] = 0;
        __syncthreads();
#pragma unroll
        for (int i = 0; i < M; ++i) {
            unsigned c = codes[i];
            if ((c & hi_mask) == prefix)
                atomicAdd(&s_hist[(c >> shift) & 255], 1);
        }
        __syncthreads();

        // suffix scan over the 256 bins (threads 0..255 = waves 0..3)
        int s = (tid < 256) ? s_hist[tid] : 0;
#pragma unroll
        for (int off = 1; off < 64; off <<= 1) {
            int o = __shfl_down(s, off, 64);
            if (lane + off < 64) s += o;
        }
        if (tid < 256 && lane == 0) s_wtot[w] = s;
        __syncthreads();
        if (tid < 256) {
            int c = s;
            for (int w2 = w + 1; w2 < 4; ++w2) c += s_wtot[w2];
            s_scum[tid] = c;
            if (tid == 0) s_scum[256] = 0;
        }
        __syncthreads();
        // cum is non-increasing; exactly one j has cum[j] >= K_rem > cum[j+1]
        if (tid < 256 && s_scum[tid] >= K_rem && s_scum[tid + 1] < K_rem) {
            s_sel   = tid;
            s_above = s_scum[tid + 1];
        }
        __syncthreads();
        prefix |= ((unsigned)s_sel) << shift;
        K_rem  -= s_above;
        __syncthreads();
    }

    float thresh = dec_f(prefix);
#pragma unroll
    for (int i = 0; i < M; ++i) {
        int   idx = tid + (i << 10);
        float v   = dec_f(codes[i]);
        float val = sigmoidf(BETA * (v - thresh));
        if (masked && codes[i] < prefix) val = 0.f;  // code order == float order
        y[idx] = val;
    }
}

template <int M>
__global__ __launch_bounds__(1024) void topk_kernel(
    const float* __restrict__ h, float* __restrict__ y, int K, int masked) {
    topk_body<M>(h, y, K, masked);
}

// Two independent top-Ks in one launch: block 0 -> (hA,yA,KA), block 1 -> (hB,yB,KB).
__global__ __launch_bounds__(1024) void topk_dual_kernel(
    const float* __restrict__ hA, float* __restrict__ yA, int KA,
    const float* __restrict__ hB, float* __restrict__ yB, int KB) {
    if (blockIdx.x == 0) topk_body<8>(hA, yA, KA, 1);
    else                 topk_body<8>(hB, yB, KB, 1);
}

// Fused BTSP update + lateral matvec, one block of 256 per row r:
//   Wout[r,c] = (1 - ALPHA*IS[r]) * W[r,c] + ALPHA*IS[r]*x_ca3[c]
//   h2[r]     = dot(W[r,:], x_ca3)      (uses OLD W, as in reference)
__global__ __launch_bounds__(256) void update_w_kernel(
    const float* __restrict__ W, const float* __restrict__ xca3,
    const float* __restrict__ IS, float* __restrict__ Wout,
    float* __restrict__ h2) {
    __shared__ float s_x[8192];
    __shared__ float s_part[4];
    int tid = threadIdx.x;
    int r = blockIdx.x;

    f4* sx4 = (f4*)s_x;
    const f4* x4 = (const f4*)xca3;
#pragma unroll
    for (int k = 0; k < 8; ++k) sx4[tid + (k << 8)] = x4[tid + (k << 8)];
    __syncthreads();

    float isr = IS[r];
    float a = 1.0f - ALPHA * isr;
    float b = ALPHA * isr;
    const f4* Wr = (const f4*)(W + (size_t)r * 8192);
    f4*       Wo = (f4*)(Wout + (size_t)r * 8192);

    float acc = 0.f;
#pragma unroll 4
    for (int k = 0; k < 8; ++k) {
        int i = tid + (k << 8);
        f4 wv = __builtin_nontemporal_load(&Wr[i]);  // read-once
        f4 xv = sx4[i];
        f4 o;
        o.x = fmaf(a, wv.x, b * xv.x);
        o.y = fmaf(a, wv.y, b * xv.y);
        o.z = fmaf(a, wv.z, b * xv.z);
        o.w = fmaf(a, wv.w, b * xv.w);
        __builtin_nontemporal_store(o, &Wo[i]);      // write-once
        acc = fmaf(wv.x, xv.x, acc);
        acc = fmaf(wv.y, xv.y, acc);
        acc = fmaf(wv.z, xv.z, acc);
        acc = fmaf(wv.w, xv.w, acc);
    }
#pragma unroll
    for (int off = 32; off > 0; off >>= 1) acc += __shfl_down(acc, off);
    if ((tid & 63) == 0) s_part[tid >> 6] = acc;
    __syncthreads();
    if (tid == 0) h2[r] = s_part[0] + s_part[1] + s_part[2] + s_part[3];
}

extern "C" void kernel_launch(void* const* d_in, const int* in_sizes, int n_in,
                              void* d_out, int out_size, void* d_ws, size_t ws_size,
                              hipStream_t stream) {
    const float* x_ei     = (const float*)d_in[0];  // 4096
    const float* W_ei_ca3 = (const float*)d_in[1];  // 8192 x 4096
    const float* W_ei_ca1 = (const float*)d_in[2];  // 8192 x 4096
    const float* W_ca3ca1 = (const float*)d_in[3];  // 8192 x 8192
    const float* W_ca1_eo = (const float*)d_in[4];  // 4096 x 8192

    float* out   = (float*)d_out;
    float* x_eo  = out;         // [4096]
    float* W_new = out + 4096;  // [8192*8192]

    float* ws   = (float*)d_ws;
    float* h1   = ws;           // 8192
    float* h3   = ws + 8192;    // 8192
    float* xca3 = ws + 16384;   // 8192
    float* IS   = ws + 24576;   // 8192
    float* h2   = ws + 32768;   // 8192
    float* xca1 = ws + 40960;   // 8192
    float* h4   = ws + 49152;   // 4096

    // h1 = W_ei_ca3 @ x_ei ; h3 = W_ei_ca1 @ x_ei   (8192 rows x 4096 cols)
    matvec_kernel<1024><<<2048, 256, 0, stream>>>(W_ei_ca3, x_ei, h1, 8192);
    matvec_kernel<1024><<<2048, 256, 0, stream>>>(W_ei_ca1, x_ei, h3, 8192);
    // x_ca3 = sparsemoid(h1, K=2, masked) ; IS = sparsemoid(h3, K=100, masked)
    topk_dual_kernel<<<2, 1024, 0, stream>>>(h1, xca3, 2, h3, IS, 100);
    // W_new + h2 fused (streams W_ca3_ca1 once)
    update_w_kernel<<<8192, 256, 0, stream>>>(W_ca3ca1, xca3, IS, W_new, h2);
    // x_ca1 = sparsemoid(h2, K=100, unmasked)
    topk_kernel<8><<<1, 1024, 0, stream>>>(h2, xca1, 100, 0);
    // h4 = W_ca1_eo @ x_ca1   (4096 rows x 8192 cols)
    matvec_kernel<2048><<<1024, 256, 0, stream>>>(W_ca1_eo, xca1, h4, 4096);
    // x_eo = sparsemoid(h4, K=50, masked)
    topk_kernel<4><<<1, 1024, 0, stream>>>(h4, x_eo, 50, 1);
}